// Round 11
// baseline (262.425 us; speedup 1.0000x reference)
//
#include <hip/hip_runtime.h>
#include <cstdint>
#include <cstddef>

// Problem constants (fixed by setup_inputs)
#define NB 4      // batch
#define NT 12     // timesteps
#define NN 2048   // nodes
#define NF 64     // in features
#define NH 4      // heads
#define ND 16     // head dim
#define NC 64     // out channels
#define MAXD 64   // max neighbors kept (Binomial(2047,16/2048): P(deg>64)~1e-19)
#define NR (NB * NT * NN)  // 98304 batched GEMM rows

typedef _Float16 f16x8 __attribute__((ext_vector_type(8)));
typedef _Float16 f16x2 __attribute__((ext_vector_type(2)));
typedef float f32x4 __attribute__((ext_vector_type(4)));

// LeakyReLU 0.2: max(v, 0.2v) is exact for both signs (2 VALU: mul+max)
#define LR(v) fmaxf((v), 0.2f * (v))
#define RCPF(x) __builtin_amdgcn_rcpf(x)

// v_fma_mix_f32: acc += w * (f32)(f16 half of d).
#define MACLO(acc, w, d)                                                      \
  asm("v_fma_mix_f32 %0, %1, %2, %0 op_sel:[0,0,0] op_sel_hi:[0,1,0]"         \
      : "+v"(acc) : "v"(w), "v"(d))
#define MACHI(acc, w, d)                                                      \
  asm("v_fma_mix_f32 %0, %1, %2, %0 op_sel:[0,1,0] op_sel_hi:[0,1,0]"         \
      : "+v"(acc) : "v"(w), "v"(d))

// ---------------------------------------------------------------------------
// Build padded adjacency lists from the additive mask (one wave/row), with
// the weight-prep work fused in as extra trailing blocks (saves a launch).
__global__ __launch_bounds__(256) void build_adj_k(
    const float* __restrict__ bias, int* __restrict__ adj, int* __restrict__ deg,
    const float* __restrict__ Wgz, const float* __restrict__ Wgh,
    const float* __restrict__ Wz,  const float* __restrict__ Wh,
    const float* __restrict__ a1z, const float* __restrict__ a2z,
    const float* __restrict__ a1h, const float* __restrict__ a2h,
    const float* __restrict__ Zb,  const float* __restrict__ Hb,
    _Float16* __restrict__ W16, float* __restrict__ biasC) {
  if (blockIdx.x >= NB * NN / 4) {          // ---- fused prep_w blocks ----
    int idx = (blockIdx.x - NB * NN / 4) * 256 + threadIdx.x;
    if (idx < 272 * 64) {
      int c = idx >> 6, k = idx & 63;
      float w;
      if (c < 64)       w = Wgz[((c >> 4) << 10) + (k << 4) + (c & 15)];
      else if (c < 128) { int q = c - 64; w = Wgh[((q >> 4) << 10) + (k << 4) + (q & 15)]; }
      else if (c < 192) w = Wz[(k << 6) + (c - 128)];
      else if (c < 256) w = Wh[(k << 6) + (c - 192)];
      else {
        int j = c - 256, h = j & 3;
        const float* Wg = (j & 4) ? Wgh : Wgz;
        const float* av = (j & 8) ? ((j & 4) ? a2h : a2z) : ((j & 4) ? a1h : a1z);
        float s = 0.f;
#pragma unroll
        for (int d = 0; d < 16; d++)
          s = fmaf(Wg[(h << 10) + (k << 4) + d], av[(h << 4) + d], s);
        w = s;
      }
      W16[idx] = (_Float16)w;
    }
    if (blockIdx.x == NB * NN / 4 && threadIdx.x < 128)
      biasC[threadIdx.x] =
          (threadIdx.x < 64) ? Zb[threadIdx.x] : Hb[threadIdx.x - 64];
    return;
  }
  int gtid = blockIdx.x * 256 + threadIdx.x;
  int wid = gtid >> 6;            // row id in [0, NB*NN)
  int lane = threadIdx.x & 63;
  const float* row = bias + (size_t)wid * NN;
  int* arow = adj + (size_t)wid * MAXD;
  int count = 0;
  for (int c0 = 0; c0 < NN; c0 += 64) {
    float v = __builtin_nontemporal_load(row + c0 + lane);  // 67 MB single-use
    bool e = (v > -1e8f);                       // edge iff mask == 0
    unsigned long long m = __ballot(e);
    int pre = __popcll(m & ((1ull << lane) - 1ull));
    if (e) {
      int pos = count + pre;
      if (pos < MAXD) arow[pos] = c0 + lane;
    }
    count += __popcll(m);
  }
  if (lane == 0) deg[wid] = count < MAXD ? count : MAXD;
}

// ---------------------------------------------------------------------------
// fp16 MFMA GEMM: [98304 x 64] @ [64 x 272], fp32 accumulate. (unchanged)
__global__ __launch_bounds__(256) void mfma_gemm_k(
    const float* __restrict__ X, const _Float16* __restrict__ W16,
    const float* __restrict__ biasC,
    uint32_t* __restrict__ gbufF, uint32_t* __restrict__ gbufS,
    float* __restrict__ fbuf) {
  __shared__ uint32_t tr[4][16 * 68];   // per-wave 16 rows x 64 cols (+pad)
  const int tid = threadIdx.x;
  const int wv = tid >> 6, lane = tid & 63;
  const int m = lane & 15, quad = lane >> 4;
  const unsigned rw = blockIdx.x * 64 + wv * 16;      // wave's row base
  uint32_t* tw = tr[wv];

  const float* xr = X + (size_t)(rw + m) * 64;
  float4 x0 = *(const float4*)(xr + quad * 8);
  float4 x1 = *(const float4*)(xr + quad * 8 + 4);
  float4 x2 = *(const float4*)(xr + 32 + quad * 8);
  float4 x3 = *(const float4*)(xr + 32 + quad * 8 + 4);
  f16x8 A0 = {(_Float16)x0.x, (_Float16)x0.y, (_Float16)x0.z, (_Float16)x0.w,
              (_Float16)x1.x, (_Float16)x1.y, (_Float16)x1.z, (_Float16)x1.w};
  f16x8 A1 = {(_Float16)x2.x, (_Float16)x2.y, (_Float16)x2.z, (_Float16)x2.w,
              (_Float16)x3.x, (_Float16)x3.y, (_Float16)x3.z, (_Float16)x3.w};

  float bzc[4], bhc[4];
#pragma unroll
  for (int j = 0; j < 4; j++) {
    bzc[j] = biasC[j * 16 + m];
    bhc[j] = biasC[64 + j * 16 + m];
  }
  const int rsub = lane >> 4, chk = lane & 15;   // readback: row-sub, chunk

  f32x4 zacc[4], zs[4];
#pragma unroll
  for (int ct = 0; ct < 17; ct++) {
    const _Float16* wp = W16 + (ct * 16 + m) * 64;
    f16x8 B0 = *(const f16x8*)(wp + quad * 8);
    f16x8 B1 = *(const f16x8*)(wp + 32 + quad * 8);
    f32x4 acc = {0.f, 0.f, 0.f, 0.f};
    acc = __builtin_amdgcn_mfma_f32_16x16x32_f16(A0, B0, acc, 0, 0, 0);
    acc = __builtin_amdgcn_mfma_f32_16x16x32_f16(A1, B1, acc, 0, 0, 0);
    // C-layout: row = quad*4 + r, col = ct*16 + m  [measured: learn_hip m89]
    if (ct < 4) {
      zacc[ct] = acc;                        // z-feat tiles, saved for pairing
    } else if (ct < 8) {
      const int j = ct - 4;                  // h-feat tile -> pack {z,h}
#pragma unroll
      for (int r = 0; r < 4; r++) {
        f16x2 pv = {(_Float16)zacc[j][r], (_Float16)acc[r]};
        tw[(quad * 4 + r) * 68 + j * 16 + m] = __builtin_bit_cast(uint32_t, pv);
      }
      if (ct == 7) {   // full-tile readback: 4 stores x (16 lanes = 256B row)
#pragma unroll
        for (int i = 0; i < 4; i++) {
          int row = i * 4 + rsub;
          uint4 v = *(const uint4*)&tw[row * 68 + chk * 4];
          *(uint4*)&gbufF[(size_t)(rw + row) * 64 + chk * 4] = v;
        }
      }
    } else if (ct < 12) {
#pragma unroll
      for (int r = 0; r < 4; r++) zs[ct - 8][r] = acc[r] + bzc[ct - 8];
    } else if (ct < 16) {
      const int j = ct - 12;
#pragma unroll
      for (int r = 0; r < 4; r++) {
        f16x2 pv = {(_Float16)zs[j][r], (_Float16)(acc[r] + bhc[j])};
        tw[(quad * 4 + r) * 68 + j * 16 + m] = __builtin_bit_cast(uint32_t, pv);
      }
      if (ct == 15) {
#pragma unroll
        for (int i = 0; i < 4; i++) {
          int row = i * 4 + rsub;
          uint4 v = *(const uint4*)&tw[row * 68 + chk * 4];
          *(uint4*)&gbufS[(size_t)(rw + row) * 64 + chk * 4] = v;
        }
      }
    } else {
      const unsigned rb = rw + quad * 4;
#pragma unroll
      for (int r = 0; r < 4; r++) fbuf[(size_t)(rb + r) * 16 + m] = acc[r];
    }
  }
}

// ---------------------------------------------------------------------------
// Attention, R11 = R10 + K=2 timesteps per wave with rotating prefetch.
//  R10 post-mortem: 16-deep gather only bought 3 us, VALUBusy stuck ~69% ->
//  the stall is the serial HEAD of each (node,t) wave: adj load -> dependent
//  scattered f2 load -> exp -> 5-deep shfl chain (~700-900cy), re-paid 12x
//  per node. Fix (R3-proven rotating structure, now at 6x machine fill so no
//  straggler bound): each wave does t0=2*by and t0+1; adjS set up once; t1's
//  feature loads issue during t0's reduce+gather; both spd dwords issue at
//  wave start. Arithmetic per (node,t) unchanged -> bit-identical.
__global__ __launch_bounds__(256, 8) void attn_k(
    const uint32_t* __restrict__ gbufF, const uint32_t* __restrict__ gbufS,
    const float* __restrict__ fbuf,
    const int* __restrict__ adj, const int* __restrict__ deg,
    const float* __restrict__ bgz, const float* __restrict__ bgh,
    uint32_t* __restrict__ abuf) {
  __shared__ int adjS[4][MAXD];         // pre-shifted neighbor BYTE offsets (<<8)
  __shared__ float wexp[4][8][68];      // stride 68 kills head-alias
  const int tid = threadIdx.x;
  const int lane = tid & 63;
  const int ws = tid >> 6;
  // batch->XCD affinity remap (bijective over grid.x = 2048):
  const int bid = blockIdx.x;
  const int g = bid & 7;                // XCD slot
  const int b = g >> 1;                 // batch owned by XCD pair
  const int grp = (bid >> 3) * 2 + (g & 1);   // node-group within batch 0..511
  const int nl = grp * 4 + ws;
  const int node = b * NN + nl;
  const int dg = deg[node];
  adjS[ws][lane] = (lane < dg) ? (adj[node * MAXD + lane] << 8) : 0;
  const int dgp = (dg + 3) & ~3;        // 4-granular pad
  const int ch = lane, hh = lane >> 4;
  const uint32_t ch4 = (uint32_t)ch << 2;
  const int sr = lane & 7, ss = lane >> 3;   // sum-reduce: row, segment
  const float bz = bgz[ch], bh = bgh[ch];

  const int t0 = blockIdx.y * 2;
  const unsigned rb0 = (unsigned)(b * NT + t0) * NN;
  const float* fb0 = fbuf + (size_t)rb0 * 16;
  const unsigned myoff = (unsigned)adjS[ws][lane] >> 2;  // fbuf byte offset

  // Prefetch t0 features + both self pre-gate dwords (addresses known now).
  float4 c1z, c1h, c2z, c2h;
  {
    const float4* p = (const float4*)(fb0 + nl * 16);
    c1z = p[0]; c1h = p[1];
    const float4* q = (const float4*)((const char*)fb0 + myoff);
    c2z = q[2]; c2h = q[3];              // lanes >= dg read row 0 (unused)
  }
  const uint32_t spd0 = gbufS[((size_t)rb0 + nl) * 64 + ch];
  const uint32_t spd1 = gbufS[((size_t)rb0 + NN + nl) * 64 + ch];

#pragma unroll
  for (int tt = 0; tt < 2; tt++) {
    const unsigned rb = rb0 + (unsigned)tt * NN;
    const char* gFc = (const char*)(gbufF + (size_t)rb * 64);

    // ---- phase 1: raw exp attention weights from prefetched regs ----
    {
      float e0 = __expf(LR(c1z.x + c2z.x));
      float e1 = __expf(LR(c1z.y + c2z.y));
      float e2 = __expf(LR(c1z.z + c2z.z));
      float e3 = __expf(LR(c1z.w + c2z.w));
      float e4 = __expf(LR(c1h.x + c2h.x));
      float e5 = __expf(LR(c1h.y + c2h.y));
      float e6 = __expf(LR(c1h.z + c2h.z));
      float e7 = __expf(LR(c1h.w + c2h.w));
      if (lane < dg) {                  // masked: pad slots get/stay 0
        wexp[ws][0][lane] = e0;
        wexp[ws][1][lane] = e1;
        wexp[ws][2][lane] = e2;
        wexp[ws][3][lane] = e3;
        wexp[ws][4][lane] = e4;
        wexp[ws][5][lane] = e5;
        wexp[ws][6][lane] = e6;
        wexp[ws][7][lane] = e7;
      } else if (tt == 0) {
#pragma unroll
        for (int k = 0; k < 8; k++) wexp[ws][k][lane] = 0.f;
      }
    }

    // ---- prefetch t1 features (hidden under reduce+gather of t0) ----
    if (tt == 0) {
      const float* fb1 = fb0 + (size_t)NN * 16;
      const float4* p = (const float4*)(fb1 + nl * 16);
      c1z = p[0]; c1h = p[1];
      const float4* q = (const float4*)((const char*)fb1 + myoff);
      c2z = q[2]; c2h = q[3];
    }

    // ---- phase 1.5: cooperative row sums (same-wave LDS ordering) ----
    float4 u0 = *(const float4*)&wexp[ws][sr][ss * 8];
    float4 u1 = *(const float4*)&wexp[ws][sr][ss * 8 + 4];
    float part = ((u0.x + u0.y) + (u0.z + u0.w)) +
                 ((u1.x + u1.y) + (u1.z + u1.w));
    part += __shfl_xor(part, 8);
    part += __shfl_xor(part, 16);
    part += __shfl_xor(part, 32);
    const float rsz = RCPF(__shfl(part, hh));     // row hh lives in lane hh
    const float rsh = RCPF(__shfl(part, 4 + hh));

    // ---- phase 2: 16-deep gather, then 8-/4-wide remainders ----
    float az = 0.f, ah = 0.f;
    const float* wz = wexp[ws][hh];
    const float* wh = wexp[ws][4 + hh];
    int mi = 0;
    for (; mi + 16 <= dgp; mi += 16) {
      int4 ma = *(const int4*)&adjS[ws][mi];
      int4 mb = *(const int4*)&adjS[ws][mi + 4];
      int4 mc = *(const int4*)&adjS[ws][mi + 8];
      int4 md = *(const int4*)&adjS[ws][mi + 12];
      uint32_t d0 = *(const uint32_t*)(gFc + ((uint32_t)ma.x + ch4));
      uint32_t d1 = *(const uint32_t*)(gFc + ((uint32_t)ma.y + ch4));
      uint32_t d2 = *(const uint32_t*)(gFc + ((uint32_t)ma.z + ch4));
      uint32_t d3 = *(const uint32_t*)(gFc + ((uint32_t)ma.w + ch4));
      uint32_t d4 = *(const uint32_t*)(gFc + ((uint32_t)mb.x + ch4));
      uint32_t d5 = *(const uint32_t*)(gFc + ((uint32_t)mb.y + ch4));
      uint32_t d6 = *(const uint32_t*)(gFc + ((uint32_t)mb.z + ch4));
      uint32_t d7 = *(const uint32_t*)(gFc + ((uint32_t)mb.w + ch4));
      uint32_t d8 = *(const uint32_t*)(gFc + ((uint32_t)mc.x + ch4));
      uint32_t d9 = *(const uint32_t*)(gFc + ((uint32_t)mc.y + ch4));
      uint32_t dA = *(const uint32_t*)(gFc + ((uint32_t)mc.z + ch4));
      uint32_t dB = *(const uint32_t*)(gFc + ((uint32_t)mc.w + ch4));
      uint32_t dC = *(const uint32_t*)(gFc + ((uint32_t)md.x + ch4));
      uint32_t dD = *(const uint32_t*)(gFc + ((uint32_t)md.y + ch4));
      uint32_t dE = *(const uint32_t*)(gFc + ((uint32_t)md.z + ch4));
      uint32_t dF = *(const uint32_t*)(gFc + ((uint32_t)md.w + ch4));
      {
        float4 wza = *(const float4*)&wz[mi];
        float4 wzb = *(const float4*)&wz[mi + 4];
        float4 wha = *(const float4*)&wh[mi];
        float4 whb = *(const float4*)&wh[mi + 4];
        MACLO(az, wza.x, d0); MACHI(ah, wha.x, d0);
        MACLO(az, wza.y, d1); MACHI(ah, wha.y, d1);
        MACLO(az, wza.z, d2); MACHI(ah, wha.z, d2);
        MACLO(az, wza.w, d3); MACHI(ah, wha.w, d3);
        MACLO(az, wzb.x, d4); MACHI(ah, whb.x, d4);
        MACLO(az, wzb.y, d5); MACHI(ah, whb.y, d5);
        MACLO(az, wzb.z, d6); MACHI(ah, whb.z, d6);
        MACLO(az, wzb.w, d7); MACHI(ah, whb.w, d7);
      }
      {
        float4 wzc = *(const float4*)&wz[mi + 8];
        float4 wzd = *(const float4*)&wz[mi + 12];
        float4 whc = *(const float4*)&wh[mi + 8];
        float4 whd = *(const float4*)&wh[mi + 12];
        MACLO(az, wzc.x, d8); MACHI(ah, whc.x, d8);
        MACLO(az, wzc.y, d9); MACHI(ah, whc.y, d9);
        MACLO(az, wzc.z, dA); MACHI(ah, whc.z, dA);
        MACLO(az, wzc.w, dB); MACHI(ah, whc.w, dB);
        MACLO(az, wzd.x, dC); MACHI(ah, whd.x, dC);
        MACLO(az, wzd.y, dD); MACHI(ah, whd.y, dD);
        MACLO(az, wzd.z, dE); MACHI(ah, whd.z, dE);
        MACLO(az, wzd.w, dF); MACHI(ah, whd.w, dF);
      }
    }
    if (mi + 8 <= dgp) {
      int4 ma = *(const int4*)&adjS[ws][mi];
      int4 mb = *(const int4*)&adjS[ws][mi + 4];
      uint32_t d0 = *(const uint32_t*)(gFc + ((uint32_t)ma.x + ch4));
      uint32_t d1 = *(const uint32_t*)(gFc + ((uint32_t)ma.y + ch4));
      uint32_t d2 = *(const uint32_t*)(gFc + ((uint32_t)ma.z + ch4));
      uint32_t d3 = *(const uint32_t*)(gFc + ((uint32_t)ma.w + ch4));
      uint32_t d4 = *(const uint32_t*)(gFc + ((uint32_t)mb.x + ch4));
      uint32_t d5 = *(const uint32_t*)(gFc + ((uint32_t)mb.y + ch4));
      uint32_t d6 = *(const uint32_t*)(gFc + ((uint32_t)mb.z + ch4));
      uint32_t d7 = *(const uint32_t*)(gFc + ((uint32_t)mb.w + ch4));
      float4 wza = *(const float4*)&wz[mi];
      float4 wzb = *(const float4*)&wz[mi + 4];
      float4 wha = *(const float4*)&wh[mi];
      float4 whb = *(const float4*)&wh[mi + 4];
      MACLO(az, wza.x, d0); MACHI(ah, wha.x, d0);
      MACLO(az, wza.y, d1); MACHI(ah, wha.y, d1);
      MACLO(az, wza.z, d2); MACHI(ah, wha.z, d2);
      MACLO(az, wza.w, d3); MACHI(ah, wha.w, d3);
      MACLO(az, wzb.x, d4); MACHI(ah, whb.x, d4);
      MACLO(az, wzb.y, d5); MACHI(ah, whb.y, d5);
      MACLO(az, wzb.z, d6); MACHI(ah, whb.z, d6);
      MACLO(az, wzb.w, d7); MACHI(ah, whb.w, d7);
      mi += 8;
    }
    if (mi < dgp) {                    // dgp is 4-granular: exactly 4 left
      int4 ma = *(const int4*)&adjS[ws][mi];
      uint32_t d0 = *(const uint32_t*)(gFc + ((uint32_t)ma.x + ch4));
      uint32_t d1 = *(const uint32_t*)(gFc + ((uint32_t)ma.y + ch4));
      uint32_t d2 = *(const uint32_t*)(gFc + ((uint32_t)ma.z + ch4));
      uint32_t d3 = *(const uint32_t*)(gFc + ((uint32_t)ma.w + ch4));
      float4 wza = *(const float4*)&wz[mi];
      float4 wha = *(const float4*)&wh[mi];
      MACLO(az, wza.x, d0); MACHI(ah, wha.x, d0);
      MACLO(az, wza.y, d1); MACHI(ah, wha.y, d1);
      MACLO(az, wza.z, d2); MACHI(ah, wha.z, d2);
      MACLO(az, wza.w, d3); MACHI(ah, wha.w, d3);
    }
    az *= rsz;
    ah *= rsh;

    // ---- epilogue: ELU + bias + self -> fp16-packed pre-gate dword ----
    f16x2 sp = __builtin_bit_cast(f16x2, tt ? spd1 : spd0);
    float vz = az + bz; vz = vz > 0.f ? vz : __expf(vz) - 1.f;
    float vh = ah + bh; vh = vh > 0.f ? vh : __expf(vh) - 1.f;
    f16x2 pre = {(_Float16)(vz + (float)sp.x), (_Float16)(vh + (float)sp.y)};
    abuf[(size_t)(rb + nl) * 64 + ch] = __builtin_bit_cast(uint32_t, pre);
  }
}

// ---------------------------------------------------------------------------
// GRU recurrence: one lane per (node, channel); 12-step serial chain on
// fp16-packed pre-gate values (25 MB coalesced read). BN fused at the end.
__global__ __launch_bounds__(256) void gru_k(
    const uint32_t* __restrict__ abuf,
    const float* __restrict__ gam, const float* __restrict__ bet,
    const float* __restrict__ mu, const float* __restrict__ var,
    float* __restrict__ out) {
  const int gtid = blockIdx.x * 256 + threadIdx.x;   // [0, NB*NN*64)
  const int node = gtid >> 6, ch = gtid & 63;
  const int b = node >> 11, nl = node & (NN - 1);
  float hc = 0.f;
#pragma unroll
  for (int t = 0; t < NT; t++) {
    f16x2 pre = __builtin_bit_cast(
        f16x2, abuf[(size_t)((b * NT + t) * NN + nl) * 64 + ch]);
    float zg = RCPF(1.f + __expf(-((float)pre.x + hc)));      // sigmoid
    float ta = (float)pre.y + hc;
    float tg = 1.f - 2.f * RCPF(__expf(2.f * ta) + 1.f);      // tanh
    hc = zg * hc + (1.f - zg) * tg;
  }
  out[gtid] = (hc - mu[ch]) * rsqrtf(var[ch] + 1e-3f) * gam[ch] + bet[ch];
}

// ---------------------------------------------------------------------------
extern "C" void kernel_launch(void* const* d_in, const int* in_sizes, int n_in,
                              void* d_out, int out_size, void* d_ws, size_t ws_size,
                              hipStream_t stream) {
  (void)in_sizes; (void)n_in; (void)out_size; (void)ws_size;
  const float* X   = (const float*)d_in[0];
  const float* bm  = (const float*)d_in[1];
  const float* Wz  = (const float*)d_in[2];
  const float* Zb  = (const float*)d_in[3];
  const float* Wh  = (const float*)d_in[4];
  const float* Hb  = (const float*)d_in[5];
  const float* Wgz = (const float*)d_in[6];
  const float* a1z = (const float*)d_in[7];
  const float* a2z = (const float*)d_in[8];
  const float* bgz = (const float*)d_in[9];
  const float* Wgh = (const float*)d_in[10];
  const float* a1h = (const float*)d_in[11];
  const float* a2h = (const float*)d_in[12];
  const float* bgh = (const float*)d_in[13];
  const float* gam = (const float*)d_in[14];
  const float* bet = (const float*)d_in[15];
  const float* mu  = (const float*)d_in[16];
  const float* var = (const float*)d_in[17];
  float* out = (float*)d_out;

  char* p = (char*)d_ws;
  uint32_t* gbufF = (uint32_t*)p; p += (size_t)NR * 64 * sizeof(uint32_t);  // 25 MB
  uint32_t* gbufS = (uint32_t*)p; p += (size_t)NR * 64 * sizeof(uint32_t);  // 25 MB
  float*    fbuf  = (float*)p;    p += (size_t)NR * 16 * sizeof(float);     // 6 MB
  uint32_t* abuf  = (uint32_t*)p; p += (size_t)NR * 64 * sizeof(uint32_t);  // 25 MB
  int*      adj   = (int*)p;      p += (size_t)NB * NN * MAXD * sizeof(int);// 2 MB
  int*      deg   = (int*)p;      p += (size_t)NB * NN * sizeof(int);       // 32 KB
  _Float16* W16   = (_Float16*)p; p += 272 * 64 * sizeof(_Float16);         // 34 KB
  float*    biasC = (float*)p;    p += 128 * sizeof(float);

  build_adj_k<<<dim3(NB * NN / 4 + 68), dim3(256), 0, stream>>>(
      bm, adj, deg, Wgz, Wgh, Wz, Wh, a1z, a2z, a1h, a2h, Zb, Hb, W16, biasC);
  mfma_gemm_k<<<dim3(NR / 64), dim3(256), 0, stream>>>(
      X, W16, biasC, gbufF, gbufS, fbuf);
  attn_k<<<dim3(NB * NN / 4, NT / 2), dim3(256), 0, stream>>>(
      gbufF, gbufS, fbuf, adj, deg, bgz, bgh, abuf);
  gru_k<<<dim3(NB * NN * 64 / 256), dim3(256), 0, stream>>>(
      abuf, gam, bet, mu, var, out);
}

// Round 12
// 231.935 us; speedup vs baseline: 1.1315x; 1.1315x over previous
//
#include <hip/hip_runtime.h>
#include <cstdint>
#include <cstddef>

// Problem constants (fixed by setup_inputs)
#define NB 4      // batch
#define NT 12     // timesteps
#define NN 2048   // nodes
#define NF 64     // in features
#define NH 4      // heads
#define ND 16     // head dim
#define NC 64     // out channels
#define MAXD 64   // max neighbors kept (Binomial(2047,16/2048): P(deg>64)~1e-19)
#define NR (NB * NT * NN)  // 98304 batched GEMM rows

typedef _Float16 f16x8 __attribute__((ext_vector_type(8)));
typedef _Float16 f16x2 __attribute__((ext_vector_type(2)));
typedef float f32x4 __attribute__((ext_vector_type(4)));

// LeakyReLU 0.2: max(v, 0.2v) is exact for both signs (2 VALU: mul+max)
#define LR(v) fmaxf((v), 0.2f * (v))
#define RCPF(x) __builtin_amdgcn_rcpf(x)

// v_fma_mix_f32: acc += w * (f32)(f16 half of d).
#define MACLO(acc, w, d)                                                      \
  asm("v_fma_mix_f32 %0, %1, %2, %0 op_sel:[0,0,0] op_sel_hi:[0,1,0]"         \
      : "+v"(acc) : "v"(w), "v"(d))
#define MACHI(acc, w, d)                                                      \
  asm("v_fma_mix_f32 %0, %1, %2, %0 op_sel:[0,1,0] op_sel_hi:[0,1,0]"         \
      : "+v"(acc) : "v"(w), "v"(d))

// ---------------------------------------------------------------------------
// Build padded adjacency lists from the additive mask (one wave/row), with
// the weight-prep work fused in as extra trailing blocks (saves a launch).
__global__ __launch_bounds__(256) void build_adj_k(
    const float* __restrict__ bias, int* __restrict__ adj, int* __restrict__ deg,
    const float* __restrict__ Wgz, const float* __restrict__ Wgh,
    const float* __restrict__ Wz,  const float* __restrict__ Wh,
    const float* __restrict__ a1z, const float* __restrict__ a2z,
    const float* __restrict__ a1h, const float* __restrict__ a2h,
    const float* __restrict__ Zb,  const float* __restrict__ Hb,
    _Float16* __restrict__ W16, float* __restrict__ biasC) {
  if (blockIdx.x >= NB * NN / 4) {          // ---- fused prep_w blocks ----
    int idx = (blockIdx.x - NB * NN / 4) * 256 + threadIdx.x;
    if (idx < 272 * 64) {
      int c = idx >> 6, k = idx & 63;
      float w;
      if (c < 64)       w = Wgz[((c >> 4) << 10) + (k << 4) + (c & 15)];
      else if (c < 128) { int q = c - 64; w = Wgh[((q >> 4) << 10) + (k << 4) + (q & 15)]; }
      else if (c < 192) w = Wz[(k << 6) + (c - 128)];
      else if (c < 256) w = Wh[(k << 6) + (c - 192)];
      else {
        int j = c - 256, h = j & 3;
        const float* Wg = (j & 4) ? Wgh : Wgz;
        const float* av = (j & 8) ? ((j & 4) ? a2h : a2z) : ((j & 4) ? a1h : a1z);
        float s = 0.f;
#pragma unroll
        for (int d = 0; d < 16; d++)
          s = fmaf(Wg[(h << 10) + (k << 4) + d], av[(h << 4) + d], s);
        w = s;
      }
      W16[idx] = (_Float16)w;
    }
    if (blockIdx.x == NB * NN / 4 && threadIdx.x < 128)
      biasC[threadIdx.x] =
          (threadIdx.x < 64) ? Zb[threadIdx.x] : Hb[threadIdx.x - 64];
    return;
  }
  int gtid = blockIdx.x * 256 + threadIdx.x;
  int wid = gtid >> 6;            // row id in [0, NB*NN)
  int lane = threadIdx.x & 63;
  const float* row = bias + (size_t)wid * NN;
  int* arow = adj + (size_t)wid * MAXD;
  int count = 0;
  for (int c0 = 0; c0 < NN; c0 += 64) {
    float v = __builtin_nontemporal_load(row + c0 + lane);  // 67 MB single-use
    bool e = (v > -1e8f);                       // edge iff mask == 0
    unsigned long long m = __ballot(e);
    int pre = __popcll(m & ((1ull << lane) - 1ull));
    if (e) {
      int pos = count + pre;
      if (pos < MAXD) arow[pos] = c0 + lane;
    }
    count += __popcll(m);
  }
  if (lane == 0) deg[wid] = count < MAXD ? count : MAXD;
}

// ---------------------------------------------------------------------------
// fp16 MFMA GEMM: [98304 x 64] @ [64 x 272], fp32 accumulate. (unchanged)
__global__ __launch_bounds__(256) void mfma_gemm_k(
    const float* __restrict__ X, const _Float16* __restrict__ W16,
    const float* __restrict__ biasC,
    uint32_t* __restrict__ gbufF, uint32_t* __restrict__ gbufS,
    float* __restrict__ fbuf) {
  __shared__ uint32_t tr[4][16 * 68];   // per-wave 16 rows x 64 cols (+pad)
  const int tid = threadIdx.x;
  const int wv = tid >> 6, lane = tid & 63;
  const int m = lane & 15, quad = lane >> 4;
  const unsigned rw = blockIdx.x * 64 + wv * 16;      // wave's row base
  uint32_t* tw = tr[wv];

  const float* xr = X + (size_t)(rw + m) * 64;
  float4 x0 = *(const float4*)(xr + quad * 8);
  float4 x1 = *(const float4*)(xr + quad * 8 + 4);
  float4 x2 = *(const float4*)(xr + 32 + quad * 8);
  float4 x3 = *(const float4*)(xr + 32 + quad * 8 + 4);
  f16x8 A0 = {(_Float16)x0.x, (_Float16)x0.y, (_Float16)x0.z, (_Float16)x0.w,
              (_Float16)x1.x, (_Float16)x1.y, (_Float16)x1.z, (_Float16)x1.w};
  f16x8 A1 = {(_Float16)x2.x, (_Float16)x2.y, (_Float16)x2.z, (_Float16)x2.w,
              (_Float16)x3.x, (_Float16)x3.y, (_Float16)x3.z, (_Float16)x3.w};

  float bzc[4], bhc[4];
#pragma unroll
  for (int j = 0; j < 4; j++) {
    bzc[j] = biasC[j * 16 + m];
    bhc[j] = biasC[64 + j * 16 + m];
  }
  const int rsub = lane >> 4, chk = lane & 15;   // readback: row-sub, chunk

  f32x4 zacc[4], zs[4];
#pragma unroll
  for (int ct = 0; ct < 17; ct++) {
    const _Float16* wp = W16 + (ct * 16 + m) * 64;
    f16x8 B0 = *(const f16x8*)(wp + quad * 8);
    f16x8 B1 = *(const f16x8*)(wp + 32 + quad * 8);
    f32x4 acc = {0.f, 0.f, 0.f, 0.f};
    acc = __builtin_amdgcn_mfma_f32_16x16x32_f16(A0, B0, acc, 0, 0, 0);
    acc = __builtin_amdgcn_mfma_f32_16x16x32_f16(A1, B1, acc, 0, 0, 0);
    // C-layout: row = quad*4 + r, col = ct*16 + m  [measured: learn_hip m89]
    if (ct < 4) {
      zacc[ct] = acc;                        // z-feat tiles, saved for pairing
    } else if (ct < 8) {
      const int j = ct - 4;                  // h-feat tile -> pack {z,h}
#pragma unroll
      for (int r = 0; r < 4; r++) {
        f16x2 pv = {(_Float16)zacc[j][r], (_Float16)acc[r]};
        tw[(quad * 4 + r) * 68 + j * 16 + m] = __builtin_bit_cast(uint32_t, pv);
      }
      if (ct == 7) {   // full-tile readback: 4 stores x (16 lanes = 256B row)
#pragma unroll
        for (int i = 0; i < 4; i++) {
          int row = i * 4 + rsub;
          uint4 v = *(const uint4*)&tw[row * 68 + chk * 4];
          *(uint4*)&gbufF[(size_t)(rw + row) * 64 + chk * 4] = v;
        }
      }
    } else if (ct < 12) {
#pragma unroll
      for (int r = 0; r < 4; r++) zs[ct - 8][r] = acc[r] + bzc[ct - 8];
    } else if (ct < 16) {
      const int j = ct - 12;
#pragma unroll
      for (int r = 0; r < 4; r++) {
        f16x2 pv = {(_Float16)zs[j][r], (_Float16)(acc[r] + bhc[j])};
        tw[(quad * 4 + r) * 68 + j * 16 + m] = __builtin_bit_cast(uint32_t, pv);
      }
      if (ct == 15) {
#pragma unroll
        for (int i = 0; i < 4; i++) {
          int row = i * 4 + rsub;
          uint4 v = *(const uint4*)&tw[row * 68 + chk * 4];
          *(uint4*)&gbufS[(size_t)(rw + row) * 64 + chk * 4] = v;
        }
      }
    } else {
      const unsigned rb = rw + quad * 4;
#pragma unroll
      for (int r = 0; r < 4; r++) fbuf[(size_t)(rb + r) * 16 + m] = acc[r];
    }
  }
}

// ---------------------------------------------------------------------------
// Attention, R12 = exact R10 revert (best measured: attn 49us, total 232.8us).
//  R11's K=2-timesteps-per-wave experiment REGRESSED (82.6us): doubling the
//  per-wave t-slab footprint overflowed the per-XCD L2 (WRITE 25->180 MB,
//  FETCH 43->112 MB, memory-bound). Locality law for this gather, now
//  triple-confirmed (R3/R6/R11): one (node,t) per wave, co-resident blocks
//  share one t-phase, batch->XCD affinity.
//  Kept levers (all measured): batch->XCD affinity remap (FETCH 125->43.5),
//  16-deep gather MLP, cooperative row-sum, fma_mix MACs, byte-offset adjS,
//  fmaxf-LR, early self pre-gate load, 4-granular pad.
__global__ __launch_bounds__(256, 8) void attn_k(
    const uint32_t* __restrict__ gbufF, const uint32_t* __restrict__ gbufS,
    const float* __restrict__ fbuf,
    const int* __restrict__ adj, const int* __restrict__ deg,
    const float* __restrict__ bgz, const float* __restrict__ bgh,
    uint32_t* __restrict__ abuf) {
  __shared__ int adjS[4][MAXD];         // pre-shifted neighbor BYTE offsets (<<8)
  __shared__ float wexp[4][8][68];      // stride 68 kills head-alias
  const int tid = threadIdx.x;
  const int lane = tid & 63;
  const int ws = tid >> 6;
  // batch->XCD affinity remap (bijective over grid.x = 2048):
  const int bid = blockIdx.x;
  const int g = bid & 7;                // XCD slot
  const int b = g >> 1;                 // batch owned by XCD pair
  const int grp = (bid >> 3) * 2 + (g & 1);   // node-group within batch 0..511
  const int nl = grp * 4 + ws;
  const int node = b * NN + nl;
  const int t = blockIdx.y;
  const int dg = deg[node];
  adjS[ws][lane] = (lane < dg) ? (adj[node * MAXD + lane] << 8) : 0;
  const int dgp = (dg + 3) & ~3;        // 4-granular pad
  const int ch = lane, hh = lane >> 4;
  const uint32_t ch4 = (uint32_t)ch << 2;
  const int sr = lane & 7, ss = lane >> 3;   // sum-reduce: row, segment

  const unsigned rb = (unsigned)(b * NT + t) * NN;
  const float* fb = fbuf + (size_t)rb * 16;
  const char* gFc = (const char*)(gbufF + (size_t)rb * 64);
  // self pre-gate dword: issue now, consumed in epilogue
  const uint32_t spd = gbufS[((size_t)rb + nl) * 64 + ch];

  // ---- phase 1: raw exp attention weights (lane = neighbor slot) ----
  {
    const float4* p = (const float4*)(fb + nl * 16);
    float4 f1z = p[0], f1h = p[1];
    if (lane < dg) {                    // exec-masked: inactive lanes load 0 B
      const float4* q = (const float4*)((const char*)fb +
                                        ((unsigned)adjS[ws][lane] >> 2));
      float4 f2z = q[2], f2h = q[3];
      wexp[ws][0][lane] = __expf(LR(f1z.x + f2z.x));
      wexp[ws][1][lane] = __expf(LR(f1z.y + f2z.y));
      wexp[ws][2][lane] = __expf(LR(f1z.z + f2z.z));
      wexp[ws][3][lane] = __expf(LR(f1z.w + f2z.w));
      wexp[ws][4][lane] = __expf(LR(f1h.x + f2h.x));
      wexp[ws][5][lane] = __expf(LR(f1h.y + f2h.y));
      wexp[ws][6][lane] = __expf(LR(f1h.z + f2h.z));
      wexp[ws][7][lane] = __expf(LR(f1h.w + f2h.w));
    } else {
#pragma unroll
      for (int k = 0; k < 8; k++) wexp[ws][k][lane] = 0.f;
    }
  }

  // ---- phase 1.5: cooperative row sums (same-wave LDS ordering) ----
  float4 u0 = *(const float4*)&wexp[ws][sr][ss * 8];
  float4 u1 = *(const float4*)&wexp[ws][sr][ss * 8 + 4];
  float part = ((u0.x + u0.y) + (u0.z + u0.w)) +
               ((u1.x + u1.y) + (u1.z + u1.w));
  part += __shfl_xor(part, 8);
  part += __shfl_xor(part, 16);
  part += __shfl_xor(part, 32);
  const float rsz = RCPF(__shfl(part, hh));       // row hh lives in lane hh
  const float rsh = RCPF(__shfl(part, 4 + hh));

  // ---- phase 2: 16-deep gather, then 8-/4-wide remainders ----
  float az = 0.f, ah = 0.f;
  const float* wz = wexp[ws][hh];
  const float* wh = wexp[ws][4 + hh];
  int mi = 0;
  for (; mi + 16 <= dgp; mi += 16) {
    int4 ma = *(const int4*)&adjS[ws][mi];
    int4 mb = *(const int4*)&adjS[ws][mi + 4];
    int4 mc = *(const int4*)&adjS[ws][mi + 8];
    int4 md = *(const int4*)&adjS[ws][mi + 12];
    uint32_t d0 = *(const uint32_t*)(gFc + ((uint32_t)ma.x + ch4));
    uint32_t d1 = *(const uint32_t*)(gFc + ((uint32_t)ma.y + ch4));
    uint32_t d2 = *(const uint32_t*)(gFc + ((uint32_t)ma.z + ch4));
    uint32_t d3 = *(const uint32_t*)(gFc + ((uint32_t)ma.w + ch4));
    uint32_t d4 = *(const uint32_t*)(gFc + ((uint32_t)mb.x + ch4));
    uint32_t d5 = *(const uint32_t*)(gFc + ((uint32_t)mb.y + ch4));
    uint32_t d6 = *(const uint32_t*)(gFc + ((uint32_t)mb.z + ch4));
    uint32_t d7 = *(const uint32_t*)(gFc + ((uint32_t)mb.w + ch4));
    uint32_t d8 = *(const uint32_t*)(gFc + ((uint32_t)mc.x + ch4));
    uint32_t d9 = *(const uint32_t*)(gFc + ((uint32_t)mc.y + ch4));
    uint32_t dA = *(const uint32_t*)(gFc + ((uint32_t)mc.z + ch4));
    uint32_t dB = *(const uint32_t*)(gFc + ((uint32_t)mc.w + ch4));
    uint32_t dC = *(const uint32_t*)(gFc + ((uint32_t)md.x + ch4));
    uint32_t dD = *(const uint32_t*)(gFc + ((uint32_t)md.y + ch4));
    uint32_t dE = *(const uint32_t*)(gFc + ((uint32_t)md.z + ch4));
    uint32_t dF = *(const uint32_t*)(gFc + ((uint32_t)md.w + ch4));
    {
      float4 wza = *(const float4*)&wz[mi];
      float4 wzb = *(const float4*)&wz[mi + 4];
      float4 wha = *(const float4*)&wh[mi];
      float4 whb = *(const float4*)&wh[mi + 4];
      MACLO(az, wza.x, d0); MACHI(ah, wha.x, d0);
      MACLO(az, wza.y, d1); MACHI(ah, wha.y, d1);
      MACLO(az, wza.z, d2); MACHI(ah, wha.z, d2);
      MACLO(az, wza.w, d3); MACHI(ah, wha.w, d3);
      MACLO(az, wzb.x, d4); MACHI(ah, whb.x, d4);
      MACLO(az, wzb.y, d5); MACHI(ah, whb.y, d5);
      MACLO(az, wzb.z, d6); MACHI(ah, whb.z, d6);
      MACLO(az, wzb.w, d7); MACHI(ah, whb.w, d7);
    }
    {
      float4 wzc = *(const float4*)&wz[mi + 8];
      float4 wzd = *(const float4*)&wz[mi + 12];
      float4 whc = *(const float4*)&wh[mi + 8];
      float4 whd = *(const float4*)&wh[mi + 12];
      MACLO(az, wzc.x, d8); MACHI(ah, whc.x, d8);
      MACLO(az, wzc.y, d9); MACHI(ah, whc.y, d9);
      MACLO(az, wzc.z, dA); MACHI(ah, whc.z, dA);
      MACLO(az, wzc.w, dB); MACHI(ah, whc.w, dB);
      MACLO(az, wzd.x, dC); MACHI(ah, whd.x, dC);
      MACLO(az, wzd.y, dD); MACHI(ah, whd.y, dD);
      MACLO(az, wzd.z, dE); MACHI(ah, whd.z, dE);
      MACLO(az, wzd.w, dF); MACHI(ah, whd.w, dF);
    }
  }
  if (mi + 8 <= dgp) {
    int4 ma = *(const int4*)&adjS[ws][mi];
    int4 mb = *(const int4*)&adjS[ws][mi + 4];
    uint32_t d0 = *(const uint32_t*)(gFc + ((uint32_t)ma.x + ch4));
    uint32_t d1 = *(const uint32_t*)(gFc + ((uint32_t)ma.y + ch4));
    uint32_t d2 = *(const uint32_t*)(gFc + ((uint32_t)ma.z + ch4));
    uint32_t d3 = *(const uint32_t*)(gFc + ((uint32_t)ma.w + ch4));
    uint32_t d4 = *(const uint32_t*)(gFc + ((uint32_t)mb.x + ch4));
    uint32_t d5 = *(const uint32_t*)(gFc + ((uint32_t)mb.y + ch4));
    uint32_t d6 = *(const uint32_t*)(gFc + ((uint32_t)mb.z + ch4));
    uint32_t d7 = *(const uint32_t*)(gFc + ((uint32_t)mb.w + ch4));
    float4 wza = *(const float4*)&wz[mi];
    float4 wzb = *(const float4*)&wz[mi + 4];
    float4 wha = *(const float4*)&wh[mi];
    float4 whb = *(const float4*)&wh[mi + 4];
    MACLO(az, wza.x, d0); MACHI(ah, wha.x, d0);
    MACLO(az, wza.y, d1); MACHI(ah, wha.y, d1);
    MACLO(az, wza.z, d2); MACHI(ah, wha.z, d2);
    MACLO(az, wza.w, d3); MACHI(ah, wha.w, d3);
    MACLO(az, wzb.x, d4); MACHI(ah, whb.x, d4);
    MACLO(az, wzb.y, d5); MACHI(ah, whb.y, d5);
    MACLO(az, wzb.z, d6); MACHI(ah, whb.z, d6);
    MACLO(az, wzb.w, d7); MACHI(ah, whb.w, d7);
    mi += 8;
  }
  if (mi < dgp) {                      // dgp is 4-granular: exactly 4 left
    int4 ma = *(const int4*)&adjS[ws][mi];
    uint32_t d0 = *(const uint32_t*)(gFc + ((uint32_t)ma.x + ch4));
    uint32_t d1 = *(const uint32_t*)(gFc + ((uint32_t)ma.y + ch4));
    uint32_t d2 = *(const uint32_t*)(gFc + ((uint32_t)ma.z + ch4));
    uint32_t d3 = *(const uint32_t*)(gFc + ((uint32_t)ma.w + ch4));
    float4 wza = *(const float4*)&wz[mi];
    float4 wha = *(const float4*)&wh[mi];
    MACLO(az, wza.x, d0); MACHI(ah, wha.x, d0);
    MACLO(az, wza.y, d1); MACHI(ah, wha.y, d1);
    MACLO(az, wza.z, d2); MACHI(ah, wha.z, d2);
    MACLO(az, wza.w, d3); MACHI(ah, wha.w, d3);
  }
  az *= rsz;
  ah *= rsh;

  // ---- epilogue: ELU + bias + self -> fp16-packed pre-gate dword ----
  f16x2 sp = __builtin_bit_cast(f16x2, spd);
  float vz = az + bgz[ch]; vz = vz > 0.f ? vz : __expf(vz) - 1.f;
  float vh = ah + bgh[ch]; vh = vh > 0.f ? vh : __expf(vh) - 1.f;
  f16x2 pre = {(_Float16)(vz + (float)sp.x), (_Float16)(vh + (float)sp.y)};
  abuf[(size_t)(rb + nl) * 64 + ch] = __builtin_bit_cast(uint32_t, pre);
}

// ---------------------------------------------------------------------------
// GRU recurrence: one lane per (node, channel); 12-step serial chain on
// fp16-packed pre-gate values (25 MB coalesced read). BN fused at the end.
__global__ __launch_bounds__(256) void gru_k(
    const uint32_t* __restrict__ abuf,
    const float* __restrict__ gam, const float* __restrict__ bet,
    const float* __restrict__ mu, const float* __restrict__ var,
    float* __restrict__ out) {
  const int gtid = blockIdx.x * 256 + threadIdx.x;   // [0, NB*NN*64)
  const int node = gtid >> 6, ch = gtid & 63;
  const int b = node >> 11, nl = node & (NN - 1);
  float hc = 0.f;
#pragma unroll
  for (int t = 0; t < NT; t++) {
    f16x2 pre = __builtin_bit_cast(
        f16x2, abuf[(size_t)((b * NT + t) * NN + nl) * 64 + ch]);
    float zg = RCPF(1.f + __expf(-((float)pre.x + hc)));      // sigmoid
    float ta = (float)pre.y + hc;
    float tg = 1.f - 2.f * RCPF(__expf(2.f * ta) + 1.f);      // tanh
    hc = zg * hc + (1.f - zg) * tg;
  }
  out[gtid] = (hc - mu[ch]) * rsqrtf(var[ch] + 1e-3f) * gam[ch] + bet[ch];
}

// ---------------------------------------------------------------------------
extern "C" void kernel_launch(void* const* d_in, const int* in_sizes, int n_in,
                              void* d_out, int out_size, void* d_ws, size_t ws_size,
                              hipStream_t stream) {
  (void)in_sizes; (void)n_in; (void)out_size; (void)ws_size;
  const float* X   = (const float*)d_in[0];
  const float* bm  = (const float*)d_in[1];
  const float* Wz  = (const float*)d_in[2];
  const float* Zb  = (const float*)d_in[3];
  const float* Wh  = (const float*)d_in[4];
  const float* Hb  = (const float*)d_in[5];
  const float* Wgz = (const float*)d_in[6];
  const float* a1z = (const float*)d_in[7];
  const float* a2z = (const float*)d_in[8];
  const float* bgz = (const float*)d_in[9];
  const float* Wgh = (const float*)d_in[10];
  const float* a1h = (const float*)d_in[11];
  const float* a2h = (const float*)d_in[12];
  const float* bgh = (const float*)d_in[13];
  const float* gam = (const float*)d_in[14];
  const float* bet = (const float*)d_in[15];
  const float* mu  = (const float*)d_in[16];
  const float* var = (const float*)d_in[17];
  float* out = (float*)d_out;

  char* p = (char*)d_ws;
  uint32_t* gbufF = (uint32_t*)p; p += (size_t)NR * 64 * sizeof(uint32_t);  // 25 MB
  uint32_t* gbufS = (uint32_t*)p; p += (size_t)NR * 64 * sizeof(uint32_t);  // 25 MB
  float*    fbuf  = (float*)p;    p += (size_t)NR * 16 * sizeof(float);     // 6 MB
  uint32_t* abuf  = (uint32_t*)p; p += (size_t)NR * 64 * sizeof(uint32_t);  // 25 MB
  int*      adj   = (int*)p;      p += (size_t)NB * NN * MAXD * sizeof(int);// 2 MB
  int*      deg   = (int*)p;      p += (size_t)NB * NN * sizeof(int);       // 32 KB
  _Float16* W16   = (_Float16*)p; p += 272 * 64 * sizeof(_Float16);         // 34 KB
  float*    biasC = (float*)p;    p += 128 * sizeof(float);

  build_adj_k<<<dim3(NB * NN / 4 + 68), dim3(256), 0, stream>>>(
      bm, adj, deg, Wgz, Wgh, Wz, Wh, a1z, a2z, a1h, a2h, Zb, Hb, W16, biasC);
  mfma_gemm_k<<<dim3(NR / 64), dim3(256), 0, stream>>>(
      X, W16, biasC, gbufF, gbufS, fbuf);
  attn_k<<<dim3(NB * NN / 4, NT), dim3(256), 0, stream>>>(
      gbufF, gbufS, fbuf, adj, deg, bgz, bgh, abuf);
  gru_k<<<dim3(NB * NN * 64 / 256), dim3(256), 0, stream>>>(
      abuf, gam, bet, mu, var, out);
}